// Round 2
// baseline (133.622 us; speedup 1.0000x reference)
//
#include <hip/hip_runtime.h>
#include <hip/hip_bf16.h>

#define VOCAB 50257
#define FEAT 512
#define NTOK (32 * 4096)
#define EPS 1e-12f

typedef float f32x4 __attribute__((ext_vector_type(4)));

__device__ __forceinline__ unsigned short f2bf(float x) {
    __hip_bfloat16 h = __float2bfloat16(x);  // RNE
    unsigned short u;
    __builtin_memcpy(&u, &h, 2);
    return u;
}

__device__ __forceinline__ float bflo(unsigned int w) {   // low bf16 -> f32
    unsigned int u = w << 16;
    float f;
    __builtin_memcpy(&f, &u, 4);
    return f;
}
__device__ __forceinline__ float bfhi(unsigned int w) {   // high bf16 -> f32
    unsigned int u = w & 0xffff0000u;
    float f;
    __builtin_memcpy(&f, &u, 4);
    return f;
}

// ---------------------------------------------------------------------------
// K1: Wt[v][f] = bf16(W[f][v] + b[f]).  64x64 tiles, LDS [64][65] (conflict-
// free both phases), coalesced 4B reads (W rows are odd-length -> no aligned
// vector loads possible), fully-coalesced bf16x8 (16B/lane) writes.
// ---------------------------------------------------------------------------
__global__ __launch_bounds__(256) void transpose_bias_bf16(
        const float* __restrict__ W, const float* __restrict__ b,
        unsigned short* __restrict__ Wt) {
    __shared__ float tile[64][65];            // [f_local][v_local]
    const int t  = threadIdx.x;
    const int l  = t & 63;                    // lane
    const int w  = t >> 6;                    // wave 0..3
    const int v0 = blockIdx.x * 64;
    const int f0 = blockIdx.y * 64;

    const int  v_in = v0 + l;
    const bool vok  = v_in < VOCAB;
#pragma unroll
    for (int k = 0; k < 16; ++k) {
        const int fl = w * 16 + k;
        const int f  = f0 + fl;
        const float x = vok ? W[(size_t)f * VOCAB + v_in] : 0.0f;
        tile[fl][l] = x + b[f];               // b[f] wave-uniform -> scalar load
    }
    __syncthreads();

    // 2 passes: idx = t + 256p; v_local = idx>>3, chunk = idx&7 (8 feats each)
    // per wave-instruction: 8 rows x 128B contiguous segments
#pragma unroll
    for (int p = 0; p < 2; ++p) {
        const int idx = t + 256 * p;
        const int vl  = idx >> 3;
        const int ch  = idx & 7;
        const int v   = v0 + vl;
        if (v < VOCAB) {
            unsigned int pk[4];
#pragma unroll
            for (int j = 0; j < 4; ++j) {
                const int f = ch * 8 + 2 * j;
                pk[j] = (unsigned int)f2bf(tile[f][vl]) |
                        ((unsigned int)f2bf(tile[f + 1][vl]) << 16);
            }
            *(uint4*)(Wt + (size_t)v * FEAT + f0 + ch * 8) =
                make_uint4(pk[0], pk[1], pk[2], pk[3]);
        }
    }
}

// ---------------------------------------------------------------------------
// K2: one wave per token. ONE dwordx4/lane fetches the whole 1KB bf16 row,
// unpack, sum-of-squares shuffle reduce, scale, nontemporal f32 stores.
// ---------------------------------------------------------------------------
__global__ __launch_bounds__(256) void encode_bf16(
        const int* __restrict__ ids, const unsigned short* __restrict__ Wt,
        float* __restrict__ out) {
    const int tok  = (int)((blockIdx.x * (unsigned long long)blockDim.x + threadIdx.x) >> 6);
    const int lane = threadIdx.x & 63;
    if (tok >= NTOK) return;

    const int id = ids[tok];
    const uint4 r = *(const uint4*)(Wt + (size_t)id * FEAT + lane * 8);

    float x[8];
    x[0] = bflo(r.x); x[1] = bfhi(r.x);
    x[2] = bflo(r.y); x[3] = bfhi(r.y);
    x[4] = bflo(r.z); x[5] = bfhi(r.z);
    x[6] = bflo(r.w); x[7] = bfhi(r.w);

    float s = 0.0f;
#pragma unroll
    for (int j = 0; j < 8; ++j) s += x[j] * x[j];
#pragma unroll
    for (int off = 32; off > 0; off >>= 1)
        s += __shfl_xor(s, off, 64);

    const float inv = 1.0f / fmaxf(sqrtf(s), EPS);

    f32x4 o0 = {x[0] * inv, x[1] * inv, x[2] * inv, x[3] * inv};
    f32x4 o1 = {x[4] * inv, x[5] * inv, x[6] * inv, x[7] * inv};
    f32x4* dst = (f32x4*)(out + (size_t)tok * FEAT + lane * 8);
    __builtin_nontemporal_store(o0, dst);
    __builtin_nontemporal_store(o1, dst + 1);
}

// ---------------------------------------------------------------------------
// Fallback (ws too small for 51.5 MB table): direct strided gather from W.
// ---------------------------------------------------------------------------
__global__ __launch_bounds__(256) void encode_direct(const int* __restrict__ ids,
                                                     const float* __restrict__ W,
                                                     const float* __restrict__ bias,
                                                     float* __restrict__ out) {
    const int tok  = (int)((blockIdx.x * (unsigned long long)blockDim.x + threadIdx.x) >> 6);
    const int lane = threadIdx.x & 63;
    if (tok >= NTOK) return;

    const int id = ids[tok];
    float x[8];
    float s = 0.0f;
#pragma unroll
    for (int j = 0; j < 8; ++j) {
        const int f = lane * 8 + j;
        x[j] = W[(size_t)f * VOCAB + id] + bias[f];
        s += x[j] * x[j];
    }
#pragma unroll
    for (int off = 32; off > 0; off >>= 1)
        s += __shfl_xor(s, off, 64);

    const float inv = 1.0f / fmaxf(sqrtf(s), EPS);
    float4 o0 = make_float4(x[0] * inv, x[1] * inv, x[2] * inv, x[3] * inv);
    float4 o1 = make_float4(x[4] * inv, x[5] * inv, x[6] * inv, x[7] * inv);
    float4* dst = (float4*)(out + (size_t)tok * FEAT + lane * 8);
    dst[0] = o0;
    dst[1] = o1;
}

extern "C" void kernel_launch(void* const* d_in, const int* in_sizes, int n_in,
                              void* d_out, int out_size, void* d_ws, size_t ws_size,
                              hipStream_t stream) {
    const int*   ids  = (const int*)d_in[0];
    const float* W    = (const float*)d_in[1];
    const float* bias = (const float*)d_in[2];
    float*       out  = (float*)d_out;

    const size_t wt_bytes = (size_t)VOCAB * FEAT * sizeof(unsigned short);
    const int nblocks = NTOK / 4;                       // 4 waves (tokens) / block

    if (ws_size >= wt_bytes) {
        unsigned short* Wt = (unsigned short*)d_ws;
        dim3 tgrid((VOCAB + 63) / 64, FEAT / 64);       // (786, 8)
        transpose_bias_bf16<<<tgrid, 256, 0, stream>>>(W, bias, Wt);
        encode_bf16<<<nblocks, 256, 0, stream>>>(ids, Wt, out);
    } else {
        encode_direct<<<nblocks, 256, 0, stream>>>(ids, W, bias, out);
    }
}

// Round 3
// 123.354 us; speedup vs baseline: 1.0832x; 1.0832x over previous
//
#include <hip/hip_runtime.h>
#include <hip/hip_bf16.h>

#define VOCAB 50257
#define FEAT 512
#define NTOK (32 * 4096)
#define EPS 1e-12f
#define NFT 8              // number of 64-row feature tiles

typedef float f32x4 __attribute__((ext_vector_type(4)));

__device__ __forceinline__ unsigned short f2bf(float x) {
    __hip_bfloat16 h = __float2bfloat16(x);  // RNE
    unsigned short u;
    __builtin_memcpy(&u, &h, 2);
    return u;
}
__device__ __forceinline__ float bfround(float x) {      // f32 -> bf16 -> f32
    return __bfloat162float(__float2bfloat16(x));
}
__device__ __forceinline__ float bflo(unsigned int w) {
    unsigned int u = w << 16; float f; __builtin_memcpy(&f, &u, 4); return f;
}
__device__ __forceinline__ float bfhi(unsigned int w) {
    unsigned int u = w & 0xffff0000u; float f; __builtin_memcpy(&f, &u, 4); return f;
}

// ---------------------------------------------------------------------------
// K1: Wt[v][f] = bf16(W[f][v] + b[f]); also per-tile partial sum-of-squares
// partial[ftile][v] = sum over this tile's 64 f of bf16-rounded x^2.
// Reads: dwordx4/lane (4 rows x 64 v per wave-instr). LDS [64][65] f32.
// ---------------------------------------------------------------------------
__global__ __launch_bounds__(256) void transpose_bias_bf16(
        const float* __restrict__ W, const float* __restrict__ b,
        unsigned short* __restrict__ Wt, float* __restrict__ partial) {
    __shared__ float tile[64][65];            // [f_local][v_local]
    __shared__ float psum[4][64];             // per-wave partial sums per v
    const int t  = threadIdx.x;
    const int l  = t & 63;
    const int w  = t >> 6;                    // wave 0..3
    const int v0 = blockIdx.x * 64;
    const int f0 = blockIdx.y * 64;
    const int c  = l & 15;                    // v-group (4 v each)
    const int r  = l >> 4;                    // f-subrow 0..3
    const int vb = v0 + c * 4;

    float p[4] = {0.f, 0.f, 0.f, 0.f};
#pragma unroll
    for (int k = 0; k < 4; ++k) {
        const int fl = w * 16 + k * 4 + r;
        const int f  = f0 + fl;
        f32x4 x;
        if (vb + 3 < VOCAB) {
            __builtin_memcpy(&x, W + (size_t)f * VOCAB + vb, 16);  // dwordx4, 4B-aligned ok
        } else {
#pragma unroll
            for (int i = 0; i < 4; ++i)
                x[i] = (vb + i < VOCAB) ? W[(size_t)f * VOCAB + vb + i] : 0.0f;
        }
        const float bf = b[f];
#pragma unroll
        for (int i = 0; i < 4; ++i) {
            const float xi = x[i] + bf;
            tile[fl][c * 4 + i] = xi;
            const float xr = bfround(xi);     // square the value K2 will see
            p[i] += xr * xr;
        }
    }

    // reduce partials across the 4 f-subrow groups (lanes l, l^16, l^32, l^48)
#pragma unroll
    for (int i = 0; i < 4; ++i) {
        float s = p[i];
        s += __shfl_xor(s, 16, 64);
        s += __shfl_xor(s, 32, 64);
        if (r == 0) psum[w][c * 4 + i] = s;   // lanes 0..15 hold wave totals
    }
    __syncthreads();

    // one thread per v: sum the 4 wave partials, store tile partial
    if (t < 64) {
        const int v = v0 + t;
        if (v < VOCAB)
            partial[blockIdx.y * VOCAB + v] =
                psum[0][t] + psum[1][t] + psum[2][t] + psum[3][t];
    }

    // write phase: Wt rows (bf16x8 chunks), coalesced 128B segments
#pragma unroll
    for (int ps = 0; ps < 2; ++ps) {
        const int idx = t + 256 * ps;
        const int vl  = idx >> 3;
        const int ch  = idx & 7;
        const int v   = v0 + vl;
        if (v < VOCAB) {
            unsigned int pk[4];
#pragma unroll
            for (int j = 0; j < 4; ++j) {
                const int f = ch * 8 + 2 * j;
                pk[j] = (unsigned int)f2bf(tile[f][vl]) |
                        ((unsigned int)f2bf(tile[f + 1][vl]) << 16);
            }
            *(uint4*)(Wt + (size_t)v * FEAT + f0 + ch * 8) =
                make_uint4(pk[0], pk[1], pk[2], pk[3]);
        }
    }
}

// ---------------------------------------------------------------------------
// K2: pure gather + scale. No reduction: norm comes from the partial table.
// ---------------------------------------------------------------------------
__global__ __launch_bounds__(256) void encode_bf16(
        const int* __restrict__ ids, const unsigned short* __restrict__ Wt,
        const float* __restrict__ partial, float* __restrict__ out) {
    const int tok  = (int)((blockIdx.x * (unsigned long long)blockDim.x + threadIdx.x) >> 6);
    const int lane = threadIdx.x & 63;
    if (tok >= NTOK) return;

    const int id = ids[tok];
    const uint4 rr = *(const uint4*)(Wt + (size_t)id * FEAT + lane * 8);

    float s = 0.0f;
#pragma unroll
    for (int j = 0; j < NFT; ++j) s += partial[j * VOCAB + id];   // L2-resident broadcasts

    const float inv = 1.0f / fmaxf(sqrtf(s), EPS);

    float x[8];
    x[0] = bflo(rr.x); x[1] = bfhi(rr.x);
    x[2] = bflo(rr.y); x[3] = bfhi(rr.y);
    x[4] = bflo(rr.z); x[5] = bfhi(rr.z);
    x[6] = bflo(rr.w); x[7] = bfhi(rr.w);

    f32x4 o0 = {x[0] * inv, x[1] * inv, x[2] * inv, x[3] * inv};
    f32x4 o1 = {x[4] * inv, x[5] * inv, x[6] * inv, x[7] * inv};
    f32x4* dst = (f32x4*)(out + (size_t)tok * FEAT + lane * 8);
    __builtin_nontemporal_store(o0, dst);
    __builtin_nontemporal_store(o1, dst + 1);
}

// ---------------------------------------------------------------------------
// Fallback (ws too small): direct strided gather from W with full reduction.
// ---------------------------------------------------------------------------
__global__ __launch_bounds__(256) void encode_direct(const int* __restrict__ ids,
                                                     const float* __restrict__ W,
                                                     const float* __restrict__ bias,
                                                     float* __restrict__ out) {
    const int tok  = (int)((blockIdx.x * (unsigned long long)blockDim.x + threadIdx.x) >> 6);
    const int lane = threadIdx.x & 63;
    if (tok >= NTOK) return;

    const int id = ids[tok];
    float x[8];
    float s = 0.0f;
#pragma unroll
    for (int j = 0; j < 8; ++j) {
        const int f = lane * 8 + j;
        x[j] = W[(size_t)f * VOCAB + id] + bias[f];
        s += x[j] * x[j];
    }
#pragma unroll
    for (int off = 32; off > 0; off >>= 1)
        s += __shfl_xor(s, off, 64);

    const float inv = 1.0f / fmaxf(sqrtf(s), EPS);
    float4 o0 = make_float4(x[0] * inv, x[1] * inv, x[2] * inv, x[3] * inv);
    float4 o1 = make_float4(x[4] * inv, x[5] * inv, x[6] * inv, x[7] * inv);
    float4* dst = (float4*)(out + (size_t)tok * FEAT + lane * 8);
    dst[0] = o0;
    dst[1] = o1;
}

extern "C" void kernel_launch(void* const* d_in, const int* in_sizes, int n_in,
                              void* d_out, int out_size, void* d_ws, size_t ws_size,
                              hipStream_t stream) {
    const int*   ids  = (const int*)d_in[0];
    const float* W    = (const float*)d_in[1];
    const float* bias = (const float*)d_in[2];
    float*       out  = (float*)d_out;

    const size_t wt_bytes   = (size_t)VOCAB * FEAT * sizeof(unsigned short); // 51.46 MB
    const size_t part_bytes = (size_t)NFT * VOCAB * sizeof(float);           // 1.6 MB
    const int nblocks = NTOK / 4;

    if (ws_size >= wt_bytes + part_bytes) {
        unsigned short* Wt = (unsigned short*)d_ws;
        float* partial     = (float*)((char*)d_ws + wt_bytes);
        dim3 tgrid((VOCAB + 63) / 64, FEAT / 64);       // (786, 8)
        transpose_bias_bf16<<<tgrid, 256, 0, stream>>>(W, bias, Wt, partial);
        encode_bf16<<<nblocks, 256, 0, stream>>>(ids, Wt, partial, out);
    } else {
        encode_direct<<<nblocks, 256, 0, stream>>>(ids, W, bias, out);
    }
}